// Round 4
// baseline (166.793 us; speedup 1.0000x reference)
//
#include <hip/hip_runtime.h>
#include <math.h>

// YOLO loss: S=7 grid, B=2 boxes, NC=20 classes, IMG=448, GRID=64.
// Inputs: preConfidence (N,7,7,2) f32 | preBoxes (N,7,7,8) f32 |
//         preCondClasses (N,7,7,20) f32 | groundTruth (N,20,4) f32 |
//         groundLabels (N,20) i32
// Output: 4 f32 [coordLoss, objLoss, noObjLoss, clsLoss]
//
// R1: same-line atomics serialized -> ws partials.           (324->150us)
// R2: float4 Phase C, 2 batches/wave, full occupancy.        (150->135us)
// R3: barrier-free wave-local encode: register scan via readlane shuffles,
//     ballot predication, no LDS in batch loop. 20%20 float4 alignment
//     means no cell-straddling quads (c0=i/5, k0=4*(i%5)).

#define S7 7
#define NCELL 49
#define NGT 20
#define NCLS 20
#define BPB 4          // waves (batches) per block per iteration
#define BPW 2          // batches per wave (outer loop)
#define THREADS 256
#define NBLK 2048      // 16384 / (BPB*BPW)

__device__ __forceinline__ float clip447(float v) {
    return fminf(fmaxf(v, 0.0f), 447.0f);
}

__device__ __forceinline__ float iou_one(float4 pb, float ltx, float lty,
                                         float g1x, float g1y, float g2x, float g2y,
                                         float ga) {
    float cx = pb.x * 64.0f + ltx, cy = pb.y * 64.0f + lty;
    float w  = pb.z * 448.0f,      h  = pb.w * 448.0f;
    float p1x = clip447(cx - w * 0.5f), p1y = clip447(cy - h * 0.5f);
    float p2x = clip447(cx + w * 0.5f), p2y = clip447(cy + h * 0.5f);
    float lx = fmaxf(p1x, g1x), ly = fmaxf(p1y, g1y);
    float rx = fminf(p2x, g2x), ry = fminf(p2y, g2y);
    float iw = fmaxf(rx - lx, 0.0f), ih = fmaxf(ry - ly, 0.0f);
    float inter = iw * ih;
    float a1 = (p2x - p1x) * (p2y - p1y);
    return inter / (a1 + ga - inter + 0.0001f);
}

__global__ __launch_bounds__(THREADS, 8) void yolo_loss_kernel(
    const float* __restrict__ preConf,   // N*49*2
    const float* __restrict__ preBoxes,  // N*49*8
    const float* __restrict__ preCls,    // N*49*20
    const float* __restrict__ gtBox,     // N*20*4
    const int*   __restrict__ gtLab,     // N*20
    float* __restrict__ ws)              // 4*NBLK partials, component-major
{
    __shared__ float s_red[BPB][4];

    const int wave = threadIdx.x >> 6;
    const int lane = threadIdx.x & 63;

    float coordL = 0.0f, objL = 0.0f, noobjL = 0.0f, clsL = 0.0f;

    for (int it = 0; it < BPW; ++it) {
        const int n = it * (NBLK * BPB) + blockIdx.x * BPB + wave;

        // ---- Phase A: GT encode fully in registers (lanes 0..19 hold GTs) ----
        float offx = 0.f, offy = 0.f, offw = 0.f, offh = 0.f;
        int flatv = 0, lab = 0;
        if (lane < NGT) {
            float4 g = reinterpret_cast<const float4*>(gtBox)[(size_t)n * NGT + lane];
            lab = gtLab[(size_t)n * NGT + lane];
            float w = g.z - g.x, h = g.w - g.y;
            float x = g.x + 0.5f * w, y = g.y + 0.5f * h;
            int cx = (int)floorf(x * 0.015625f);   // /64, x in [0,447] -> cx in [0,6]
            int cy = (int)floorf(y * 0.015625f);
            flatv = cy * S7 + cx;
            offx = (x - (float)cx * 64.0f) * 0.015625f;
            offy = (y - (float)cy * 64.0f) * 0.015625f;
            offw = w * (1.0f / 448.0f);
            offh = h * (1.0f / 448.0f);
        }

        // In-wave scan: lane c (cell id) collects last-GT index + label bits.
        // Literal j -> v_readlane broadcast; no LDS, no barriers.
        int last = -1;
        unsigned bits = 0u;
        #pragma unroll
        for (int j = 0; j < NGT; ++j) {
            int fj = __shfl(flatv, j);
            int lj = __shfl(lab, j);
            if (fj == lane) { last = j; bits |= (1u << lj); }
        }
        const unsigned long long ball = __ballot(bits != 0u); // obj-cell mask, all lanes

        // Gather winning GT's offset vector from lane `last` (bpermute x4).
        const int srcl = (last < 0) ? 0 : last;
        const float gx = __shfl(offx, srcl);
        const float gy = __shfl(offy, srcl);
        const float gw = __shfl(offw, srcl);
        const float gh = __shfl(offh, srcl);

        // ---- Phase B: per-cell boxes/conf (lanes 0..48) ----
        if (lane < NCELL) {
            const int row = lane / S7, col = lane - row * S7;
            const float ltx = (float)col * 64.0f, lty = (float)row * 64.0f;

            float2 cf = reinterpret_cast<const float2*>(preConf)[(size_t)n * NCELL + lane];
            if (last >= 0) {
                const float4* pbp = reinterpret_cast<const float4*>(preBoxes)
                                    + (size_t)n * NCELL * 2 + (size_t)lane * 2;
                float4 b0 = pbp[0];
                float4 b1 = pbp[1];

                float gcx = gx * 64.0f + ltx, gcy = gy * 64.0f + lty;
                float gW = gw * 448.0f, gH = gh * 448.0f;
                float g1x = clip447(gcx - gW * 0.5f), g1y = clip447(gcy - gH * 0.5f);
                float g2x = clip447(gcx + gW * 0.5f), g2y = clip447(gcy + gH * 0.5f);
                float ga = (g2x - g1x) * (g2y - g1y);

                float iou0 = iou_one(b0, ltx, lty, g1x, g1y, g2x, g2y, ga);
                float iou1 = iou_one(b1, ltx, lty, g1x, g1y, g2x, g2y, ga);
                int best = (iou1 > iou0) ? 1 : 0;        // jnp.argmax: first max wins
                float4 pb = best ? b1 : b0;
                float confB = best ? cf.y : cf.x;
                float confO = best ? cf.x : cf.y;

                float dx = pb.x - gx, dy = pb.y - gy;
                float dw = sqrtf(pb.z) - sqrtf(gw);
                float dh = sqrtf(pb.w) - sqrtf(gh);
                coordL += dx * dx + dy * dy + dw * dw + dh * dh;
                float d = confB - 1.0f;
                objL += d * d;
                noobjL += confO * confO;
            } else {
                noobjL += cf.x * cf.x + cf.y * cf.y;
            }
        }

        // ---- Phase C: class loss, float4, ballot-predicated ----
        // 245 float4s; 20%4==0 so each quad lies in one cell: c0=i/5, k0=4*(i%5).
        {
            const float4* base4 = reinterpret_cast<const float4*>(
                preCls + (size_t)n * (NCELL * NCLS));
            #pragma unroll
            for (int t = 0; t < 4; ++t) {
                const int i = lane + t * 64;
                if (i < 245) {
                    const int c0 = i / 5;
                    const int k0 = (i - c0 * 5) * 4;
                    if ((ball >> c0) & 1ull) {
                        const unsigned b = __shfl(bits, c0);
                        float4 v = base4[i];
                        float d0 = v.x - (float)((b >> (k0 + 0)) & 1u);
                        float d1 = v.y - (float)((b >> (k0 + 1)) & 1u);
                        float d2 = v.z - (float)((b >> (k0 + 2)) & 1u);
                        float d3 = v.w - (float)((b >> (k0 + 3)) & 1u);
                        clsL += d0 * d0 + d1 * d1 + d2 * d2 + d3 * d3;
                    }
                }
            }
        }
    }

    // ---- wave reduce (64 lanes) ----
    for (int off = 32; off > 0; off >>= 1) {
        coordL += __shfl_down(coordL, off);
        objL   += __shfl_down(objL, off);
        noobjL += __shfl_down(noobjL, off);
        clsL   += __shfl_down(clsL, off);
    }
    if (lane == 0) {
        s_red[wave][0] = coordL;
        s_red[wave][1] = objL;
        s_red[wave][2] = noobjL;
        s_red[wave][3] = clsL;
    }
    __syncthreads();

    if (threadIdx.x == 0) {
        float c0 = 0.f, c1 = 0.f, c2 = 0.f, c3 = 0.f;
        for (int w = 0; w < BPB; ++w) {
            c0 += s_red[w][0];
            c1 += s_red[w][1];
            c2 += s_red[w][2];
            c3 += s_red[w][3];
        }
        ws[0 * NBLK + blockIdx.x] = c0 * 5.0f;   // COORD_W
        ws[1 * NBLK + blockIdx.x] = c1;
        ws[2 * NBLK + blockIdx.x] = c2 * 0.5f;   // NOOBJ_W
        ws[3 * NBLK + blockIdx.x] = c3;
    }
}

// One wave per loss component; coalesced reads of its NBLK partials.
__global__ __launch_bounds__(256) void reduce_kernel(
    const float* __restrict__ ws, float* __restrict__ out)
{
    const int wave = threadIdx.x >> 6;   // 0..3 = component
    const int lane = threadIdx.x & 63;
    const float* src = ws + wave * NBLK;
    float s = 0.0f;
    for (int i = lane; i < NBLK; i += 64) s += src[i];
    for (int off = 32; off > 0; off >>= 1) s += __shfl_down(s, off);
    if (lane == 0) out[wave] = s;
}

extern "C" void kernel_launch(void* const* d_in, const int* in_sizes, int n_in,
                              void* d_out, int out_size, void* d_ws, size_t ws_size,
                              hipStream_t stream) {
    const float* preConf  = (const float*)d_in[0];
    const float* preBoxes = (const float*)d_in[1];
    const float* preCls   = (const float*)d_in[2];
    const float* gtBox    = (const float*)d_in[3];
    const int*   gtLab    = (const int*)d_in[4];
    float* out = (float*)d_out;
    float* ws  = (float*)d_ws;

    yolo_loss_kernel<<<NBLK, THREADS, 0, stream>>>(
        preConf, preBoxes, preCls, gtBox, gtLab, ws);
    reduce_kernel<<<1, 256, 0, stream>>>(ws, out);
}

// Round 5
// 142.029 us; speedup vs baseline: 1.1744x; 1.1744x over previous
//
#include <hip/hip_runtime.h>
#include <math.h>

// YOLO loss: S=7 grid, B=2 boxes, NC=20 classes, IMG=448, GRID=64.
// Inputs: preConfidence (N,7,7,2) f32 | preBoxes (N,7,7,8) f32 |
//         preCondClasses (N,7,7,20) f32 | groundTruth (N,20,4) f32 |
//         groundLabels (N,20) i32
// Output: 4 f32 [coordLoss, objLoss, noObjLoss, clsLoss]
//
// R1: same-line atomics serialized -> ws partials.           (324->150us)
// R2: float4 Phase C, 2 batches/wave, full occupancy.        (150->135us)
// R3: LDS encode, no spills                                  (135us)
// R4: FAILED: __launch_bounds__(256,8) capped VGPR=32 -> scratch spills
//     (WRITE_SIZE 66MB, FETCH 94MB, kernel 59us). Lesson: don't cap
//     registers below what the register-resident design needs.
// R5: same barrier-free shuffle-encode structure, no min-waves clause.

#define S7 7
#define NCELL 49
#define NGT 20
#define NCLS 20
#define BPB 4          // waves (batches) per block per iteration
#define BPW 2          // batches per wave (outer loop)
#define THREADS 256
#define NBLK 2048      // 16384 / (BPB*BPW)

__device__ __forceinline__ float clip447(float v) {
    return fminf(fmaxf(v, 0.0f), 447.0f);
}

__device__ __forceinline__ float iou_one(float4 pb, float ltx, float lty,
                                         float g1x, float g1y, float g2x, float g2y,
                                         float ga) {
    float cx = pb.x * 64.0f + ltx, cy = pb.y * 64.0f + lty;
    float w  = pb.z * 448.0f,      h  = pb.w * 448.0f;
    float p1x = clip447(cx - w * 0.5f), p1y = clip447(cy - h * 0.5f);
    float p2x = clip447(cx + w * 0.5f), p2y = clip447(cy + h * 0.5f);
    float lx = fmaxf(p1x, g1x), ly = fmaxf(p1y, g1y);
    float rx = fminf(p2x, g2x), ry = fminf(p2y, g2y);
    float iw = fmaxf(rx - lx, 0.0f), ih = fmaxf(ry - ly, 0.0f);
    float inter = iw * ih;
    float a1 = (p2x - p1x) * (p2y - p1y);
    return inter / (a1 + ga - inter + 0.0001f);
}

__global__ __launch_bounds__(THREADS) void yolo_loss_kernel(
    const float* __restrict__ preConf,   // N*49*2
    const float* __restrict__ preBoxes,  // N*49*8
    const float* __restrict__ preCls,    // N*49*20
    const float* __restrict__ gtBox,     // N*20*4
    const int*   __restrict__ gtLab,     // N*20
    float* __restrict__ ws)              // 4*NBLK partials, component-major
{
    __shared__ float s_red[BPB][4];

    const int wave = threadIdx.x >> 6;
    const int lane = threadIdx.x & 63;

    float coordL = 0.0f, objL = 0.0f, noobjL = 0.0f, clsL = 0.0f;

    for (int it = 0; it < BPW; ++it) {
        const int n = it * (NBLK * BPB) + blockIdx.x * BPB + wave;

        // ---- Phase A: GT encode fully in registers (lanes 0..19 hold GTs) ----
        float offx = 0.f, offy = 0.f, offw = 0.f, offh = 0.f;
        int flatv = 0, lab = 0;
        if (lane < NGT) {
            float4 g = reinterpret_cast<const float4*>(gtBox)[(size_t)n * NGT + lane];
            lab = gtLab[(size_t)n * NGT + lane];
            float w = g.z - g.x, h = g.w - g.y;
            float x = g.x + 0.5f * w, y = g.y + 0.5f * h;
            int cx = (int)floorf(x * 0.015625f);   // /64, x in [0,447] -> cx in [0,6]
            int cy = (int)floorf(y * 0.015625f);
            flatv = cy * S7 + cx;
            offx = (x - (float)cx * 64.0f) * 0.015625f;
            offy = (y - (float)cy * 64.0f) * 0.015625f;
            offw = w * (1.0f / 448.0f);
            offh = h * (1.0f / 448.0f);
        }

        // In-wave scan: lane c (cell id) collects last-GT index + label bits.
        // Literal j -> v_readlane broadcast; no LDS, no barriers.
        int last = -1;
        unsigned bits = 0u;
        #pragma unroll
        for (int j = 0; j < NGT; ++j) {
            int fj = __shfl(flatv, j);
            int lj = __shfl(lab, j);
            if (fj == lane) { last = j; bits |= (1u << lj); }
        }
        const unsigned long long ball = __ballot(bits != 0u); // obj-cell mask, all lanes

        // Gather winning GT's offset vector from lane `last`.
        const int srcl = (last < 0) ? 0 : last;
        const float gx = __shfl(offx, srcl);
        const float gy = __shfl(offy, srcl);
        const float gw = __shfl(offw, srcl);
        const float gh = __shfl(offh, srcl);

        // ---- Phase B: per-cell boxes/conf (lanes 0..48) ----
        if (lane < NCELL) {
            const int row = lane / S7, col = lane - row * S7;
            const float ltx = (float)col * 64.0f, lty = (float)row * 64.0f;

            float2 cf = reinterpret_cast<const float2*>(preConf)[(size_t)n * NCELL + lane];
            if (last >= 0) {
                const float4* pbp = reinterpret_cast<const float4*>(preBoxes)
                                    + (size_t)n * NCELL * 2 + (size_t)lane * 2;
                float4 b0 = pbp[0];
                float4 b1 = pbp[1];

                float gcx = gx * 64.0f + ltx, gcy = gy * 64.0f + lty;
                float gW = gw * 448.0f, gH = gh * 448.0f;
                float g1x = clip447(gcx - gW * 0.5f), g1y = clip447(gcy - gH * 0.5f);
                float g2x = clip447(gcx + gW * 0.5f), g2y = clip447(gcy + gH * 0.5f);
                float ga = (g2x - g1x) * (g2y - g1y);

                float iou0 = iou_one(b0, ltx, lty, g1x, g1y, g2x, g2y, ga);
                float iou1 = iou_one(b1, ltx, lty, g1x, g1y, g2x, g2y, ga);
                int best = (iou1 > iou0) ? 1 : 0;        // jnp.argmax: first max wins
                float4 pb = best ? b1 : b0;
                float confB = best ? cf.y : cf.x;
                float confO = best ? cf.x : cf.y;

                float dx = pb.x - gx, dy = pb.y - gy;
                float dw = sqrtf(pb.z) - sqrtf(gw);
                float dh = sqrtf(pb.w) - sqrtf(gh);
                coordL += dx * dx + dy * dy + dw * dw + dh * dh;
                float d = confB - 1.0f;
                objL += d * d;
                noobjL += confO * confO;
            } else {
                noobjL += cf.x * cf.x + cf.y * cf.y;
            }
        }

        // ---- Phase C: class loss, float4, ballot-predicated ----
        // 245 float4s; 20%4==0 so each quad lies in one cell: c0=i/5, k0=4*(i%5).
        {
            const float4* base4 = reinterpret_cast<const float4*>(
                preCls + (size_t)n * (NCELL * NCLS));
            #pragma unroll
            for (int t = 0; t < 4; ++t) {
                const int i = lane + t * 64;
                if (i < 245) {
                    const int c0 = i / 5;
                    const int k0 = (i - c0 * 5) * 4;
                    if ((ball >> c0) & 1ull) {
                        const unsigned b = __shfl(bits, c0);
                        float4 v = base4[i];
                        float d0 = v.x - (float)((b >> (k0 + 0)) & 1u);
                        float d1 = v.y - (float)((b >> (k0 + 1)) & 1u);
                        float d2 = v.z - (float)((b >> (k0 + 2)) & 1u);
                        float d3 = v.w - (float)((b >> (k0 + 3)) & 1u);
                        clsL += d0 * d0 + d1 * d1 + d2 * d2 + d3 * d3;
                    }
                }
            }
        }
    }

    // ---- wave reduce (64 lanes) ----
    for (int off = 32; off > 0; off >>= 1) {
        coordL += __shfl_down(coordL, off);
        objL   += __shfl_down(objL, off);
        noobjL += __shfl_down(noobjL, off);
        clsL   += __shfl_down(clsL, off);
    }
    if (lane == 0) {
        s_red[wave][0] = coordL;
        s_red[wave][1] = objL;
        s_red[wave][2] = noobjL;
        s_red[wave][3] = clsL;
    }
    __syncthreads();

    if (threadIdx.x == 0) {
        float c0 = 0.f, c1 = 0.f, c2 = 0.f, c3 = 0.f;
        for (int w = 0; w < BPB; ++w) {
            c0 += s_red[w][0];
            c1 += s_red[w][1];
            c2 += s_red[w][2];
            c3 += s_red[w][3];
        }
        ws[0 * NBLK + blockIdx.x] = c0 * 5.0f;   // COORD_W
        ws[1 * NBLK + blockIdx.x] = c1;
        ws[2 * NBLK + blockIdx.x] = c2 * 0.5f;   // NOOBJ_W
        ws[3 * NBLK + blockIdx.x] = c3;
    }
}

// One wave per loss component; coalesced reads of its NBLK partials.
__global__ __launch_bounds__(256) void reduce_kernel(
    const float* __restrict__ ws, float* __restrict__ out)
{
    const int wave = threadIdx.x >> 6;   // 0..3 = component
    const int lane = threadIdx.x & 63;
    const float* src = ws + wave * NBLK;
    float s = 0.0f;
    for (int i = lane; i < NBLK; i += 64) s += src[i];
    for (int off = 32; off > 0; off >>= 1) s += __shfl_down(s, off);
    if (lane == 0) out[wave] = s;
}

extern "C" void kernel_launch(void* const* d_in, const int* in_sizes, int n_in,
                              void* d_out, int out_size, void* d_ws, size_t ws_size,
                              hipStream_t stream) {
    const float* preConf  = (const float*)d_in[0];
    const float* preBoxes = (const float*)d_in[1];
    const float* preCls   = (const float*)d_in[2];
    const float* gtBox    = (const float*)d_in[3];
    const int*   gtLab    = (const int*)d_in[4];
    float* out = (float*)d_out;
    float* ws  = (float*)d_ws;

    yolo_loss_kernel<<<NBLK, THREADS, 0, stream>>>(
        preConf, preBoxes, preCls, gtBox, gtLab, ws);
    reduce_kernel<<<1, 256, 0, stream>>>(ws, out);
}

// Round 6
// 135.623 us; speedup vs baseline: 1.2298x; 1.0472x over previous
//
#include <hip/hip_runtime.h>
#include <math.h>

// YOLO loss: S=7 grid, B=2 boxes, NC=20 classes, IMG=448, GRID=64.
// Inputs: preConfidence (N,7,7,2) f32 | preBoxes (N,7,7,8) f32 |
//         preCondClasses (N,7,7,20) f32 | groundTruth (N,20,4) f32 |
//         groundLabels (N,20) i32
// Output: 4 f32 [coordLoss, objLoss, noObjLoss, clsLoss]
//
// R1: same-line atomics serialized -> ws partials.           (324->150us)
// R2: float4 Phase C, 2 batches/wave, full occupancy.        (150->135us)
// R3: LDS encode + BPW=2                                     (135us)
// R4: FAILED: launch_bounds(256,8) -> VGPR=32 -> spills      (167us)
// R5: shuffle encode, no reg cap                             (142us)
// R6: software-pipelined: both batches' gt/conf loads at wave start,
//     packed 1-readlane scan, predicated boxes/cls loads issued early,
//     compute overlapped with in-flight loads. Kernel was ~3 serial HBM
//     round-trips per batch; now ~2 total with batch1 fully overlapped.

#define S7 7
#define NCELL 49
#define NGT 20
#define NCLS 20
#define BPB 4          // waves (batches) per block
#define THREADS 256
#define NBLK 2048      // grid; each wave does batches n0 and n0+NBLK*BPB

__device__ __forceinline__ float clip447(float v) {
    return fminf(fmaxf(v, 0.0f), 447.0f);
}

__device__ __forceinline__ float iou_one(float4 pb, float ltx, float lty,
                                         float g1x, float g1y, float g2x, float g2y,
                                         float ga) {
    float cx = pb.x * 64.0f + ltx, cy = pb.y * 64.0f + lty;
    float w  = pb.z * 448.0f,      h  = pb.w * 448.0f;
    float p1x = clip447(cx - w * 0.5f), p1y = clip447(cy - h * 0.5f);
    float p2x = clip447(cx + w * 0.5f), p2y = clip447(cy + h * 0.5f);
    float lx = fmaxf(p1x, g1x), ly = fmaxf(p1y, g1y);
    float rx = fminf(p2x, g2x), ry = fminf(p2y, g2y);
    float iw = fmaxf(rx - lx, 0.0f), ih = fmaxf(ry - ly, 0.0f);
    float inter = iw * ih;
    float a1 = (p2x - p1x) * (p2y - p1y);
    return inter / (a1 + ga - inter + 0.0001f);
}

__global__ __launch_bounds__(THREADS) void yolo_loss_kernel(
    const float* __restrict__ preConf,   // N*49*2
    const float* __restrict__ preBoxes,  // N*49*8
    const float* __restrict__ preCls,    // N*49*20
    const float* __restrict__ gtBox,     // N*20*4
    const int*   __restrict__ gtLab,     // N*20
    float* __restrict__ ws)              // 4*NBLK partials, component-major
{
    __shared__ float s_red[BPB][4];

    const int wave = threadIdx.x >> 6;
    const int lane = threadIdx.x & 63;
    const int n0 = blockIdx.x * BPB + wave;
    const int n1 = n0 + NBLK * BPB;

    // ================= early loads: gt + labels + conf, BOTH batches =========
    float4 g0, g1;
    int pk0 = 0, pk1 = 0;
    if (lane < NGT) {
        g0 = reinterpret_cast<const float4*>(gtBox)[(size_t)n0 * NGT + lane];
        g1 = reinterpret_cast<const float4*>(gtBox)[(size_t)n1 * NGT + lane];
        pk0 = gtLab[(size_t)n0 * NGT + lane] << 8;
        pk1 = gtLab[(size_t)n1 * NGT + lane] << 8;
    }
    float2 cf0, cf1;
    if (lane < NCELL) {
        cf0 = reinterpret_cast<const float2*>(preConf)[(size_t)n0 * NCELL + lane];
        cf1 = reinterpret_cast<const float2*>(preConf)[(size_t)n1 * NCELL + lane];
    }

    // ================= encode GT -> (flat | label<<8), offsets ===============
    float ox0 = 0, oy0 = 0, ow0 = 0, oh0 = 0;
    float ox1 = 0, oy1 = 0, ow1 = 0, oh1 = 0;
    if (lane < NGT) {
        {
            float w = g0.z - g0.x, h = g0.w - g0.y;
            float x = g0.x + 0.5f * w, y = g0.y + 0.5f * h;
            int cx = (int)floorf(x * 0.015625f);
            int cy = (int)floorf(y * 0.015625f);
            pk0 |= cy * S7 + cx;
            ox0 = (x - (float)cx * 64.0f) * 0.015625f;
            oy0 = (y - (float)cy * 64.0f) * 0.015625f;
            ow0 = w * (1.0f / 448.0f);
            oh0 = h * (1.0f / 448.0f);
        }
        {
            float w = g1.z - g1.x, h = g1.w - g1.y;
            float x = g1.x + 0.5f * w, y = g1.y + 0.5f * h;
            int cx = (int)floorf(x * 0.015625f);
            int cy = (int)floorf(y * 0.015625f);
            pk1 |= cy * S7 + cx;
            ox1 = (x - (float)cx * 64.0f) * 0.015625f;
            oy1 = (y - (float)cy * 64.0f) * 0.015625f;
            ow1 = w * (1.0f / 448.0f);
            oh1 = h * (1.0f / 448.0f);
        }
    }

    // ================= in-wave scan (1 readlane per GT per batch) ============
    int last0 = -1, last1 = -1;
    unsigned bits0 = 0u, bits1 = 0u;
    #pragma unroll
    for (int j = 0; j < NGT; ++j) {
        int p0 = __shfl(pk0, j);
        int p1 = __shfl(pk1, j);
        if ((p0 & 63) == lane) { last0 = j; bits0 |= (1u << (p0 >> 8)); }
        if ((p1 & 63) == lane) { last1 = j; bits1 |= (1u << (p1 >> 8)); }
    }
    const unsigned long long ball0 = __ballot(bits0 != 0u);
    const unsigned long long ball1 = __ballot(bits1 != 0u);

    // gather winning GT offsets from lane last (bpermute)
    const int s0 = (last0 < 0) ? 0 : last0;
    const int s1 = (last1 < 0) ? 0 : last1;
    const float gx0 = __shfl(ox0, s0), gy0 = __shfl(oy0, s0);
    const float gw0 = __shfl(ow0, s0), gh0 = __shfl(oh0, s0);
    const float gx1 = __shfl(ox1, s1), gy1 = __shfl(oy1, s1);
    const float gw1 = __shfl(ow1, s1), gh1 = __shfl(oh1, s1);

    // ================= issue predicated box loads, BOTH batches ==============
    const bool obj0 = (lane < NCELL) && (last0 >= 0);
    const bool obj1 = (lane < NCELL) && (last1 >= 0);
    float4 b00, b01, b10, b11;
    if (obj0) {
        const float4* p = reinterpret_cast<const float4*>(preBoxes)
                          + (size_t)n0 * NCELL * 2 + (size_t)lane * 2;
        b00 = p[0]; b01 = p[1];
    }
    if (obj1) {
        const float4* p = reinterpret_cast<const float4*>(preBoxes)
                          + (size_t)n1 * NCELL * 2 + (size_t)lane * 2;
        b10 = p[0]; b11 = p[1];
    }

    // ================= issue cls0 loads (predicated) =========================
    // 245 float4s; 20%4==0 -> quad never straddles cells: c=i/5, k=4*(i%5).
    float4 cv0[4];
    bool   cp0[4];
    {
        const float4* base4 = reinterpret_cast<const float4*>(
            preCls + (size_t)n0 * (NCELL * NCLS));
        #pragma unroll
        for (int t = 0; t < 4; ++t) {
            const int i = lane + t * 64;
            const int c = i / 5;
            cp0[t] = (i < 245) && ((ball0 >> c) & 1ull);
            if (cp0[t]) cv0[t] = base4[i];
        }
    }

    float coordL = 0.0f, objL = 0.0f, noobjL = 0.0f, clsL = 0.0f;

    // ================= Phase B compute, batch 0 then batch 1 =================
    const int row = lane / S7, col = lane - row * S7;
    const float ltx = (float)col * 64.0f, lty = (float)row * 64.0f;

    if (lane < NCELL) {
        if (obj0) {
            float gcx = gx0 * 64.0f + ltx, gcy = gy0 * 64.0f + lty;
            float gW = gw0 * 448.0f, gH = gh0 * 448.0f;
            float g1x = clip447(gcx - gW * 0.5f), g1y = clip447(gcy - gH * 0.5f);
            float g2x = clip447(gcx + gW * 0.5f), g2y = clip447(gcy + gH * 0.5f);
            float ga = (g2x - g1x) * (g2y - g1y);
            float iou0 = iou_one(b00, ltx, lty, g1x, g1y, g2x, g2y, ga);
            float iou1 = iou_one(b01, ltx, lty, g1x, g1y, g2x, g2y, ga);
            int best = (iou1 > iou0) ? 1 : 0;        // jnp.argmax: first max wins
            float4 pb = best ? b01 : b00;
            float confB = best ? cf0.y : cf0.x;
            float confO = best ? cf0.x : cf0.y;
            float dx = pb.x - gx0, dy = pb.y - gy0;
            float dw = sqrtf(pb.z) - sqrtf(gw0);
            float dh = sqrtf(pb.w) - sqrtf(gh0);
            coordL += dx * dx + dy * dy + dw * dw + dh * dh;
            float d = confB - 1.0f;
            objL += d * d;
            noobjL += confO * confO;
        } else {
            noobjL += cf0.x * cf0.x + cf0.y * cf0.y;
        }
        if (obj1) {
            float gcx = gx1 * 64.0f + ltx, gcy = gy1 * 64.0f + lty;
            float gW = gw1 * 448.0f, gH = gh1 * 448.0f;
            float g1x = clip447(gcx - gW * 0.5f), g1y = clip447(gcy - gH * 0.5f);
            float g2x = clip447(gcx + gW * 0.5f), g2y = clip447(gcy + gH * 0.5f);
            float ga = (g2x - g1x) * (g2y - g1y);
            float iou0 = iou_one(b10, ltx, lty, g1x, g1y, g2x, g2y, ga);
            float iou1 = iou_one(b11, ltx, lty, g1x, g1y, g2x, g2y, ga);
            int best = (iou1 > iou0) ? 1 : 0;
            float4 pb = best ? b11 : b10;
            float confB = best ? cf1.y : cf1.x;
            float confO = best ? cf1.x : cf1.y;
            float dx = pb.x - gx1, dy = pb.y - gy1;
            float dw = sqrtf(pb.z) - sqrtf(gw1);
            float dh = sqrtf(pb.w) - sqrtf(gh1);
            coordL += dx * dx + dy * dy + dw * dw + dh * dh;
            float d = confB - 1.0f;
            objL += d * d;
            noobjL += confO * confO;
        } else {
            noobjL += cf1.x * cf1.x + cf1.y * cf1.y;
        }
    }

    // ================= issue cls1 loads (overlap with C0 compute) ============
    float4 cv1[4];
    bool   cp1[4];
    {
        const float4* base4 = reinterpret_cast<const float4*>(
            preCls + (size_t)n1 * (NCELL * NCLS));
        #pragma unroll
        for (int t = 0; t < 4; ++t) {
            const int i = lane + t * 64;
            const int c = i / 5;
            cp1[t] = (i < 245) && ((ball1 >> c) & 1ull);
            if (cp1[t]) cv1[t] = base4[i];
        }
    }

    // ================= Phase C compute =======================================
    #pragma unroll
    for (int t = 0; t < 4; ++t) {
        if (cp0[t]) {
            const int i = lane + t * 64;
            const int c = i / 5;
            const int k0 = (i - c * 5) * 4;
            const unsigned b = __shfl(bits0, c);
            float d0 = cv0[t].x - (float)((b >> (k0 + 0)) & 1u);
            float d1 = cv0[t].y - (float)((b >> (k0 + 1)) & 1u);
            float d2 = cv0[t].z - (float)((b >> (k0 + 2)) & 1u);
            float d3 = cv0[t].w - (float)((b >> (k0 + 3)) & 1u);
            clsL += d0 * d0 + d1 * d1 + d2 * d2 + d3 * d3;
        }
    }
    #pragma unroll
    for (int t = 0; t < 4; ++t) {
        if (cp1[t]) {
            const int i = lane + t * 64;
            const int c = i / 5;
            const int k0 = (i - c * 5) * 4;
            const unsigned b = __shfl(bits1, c);
            float d0 = cv1[t].x - (float)((b >> (k0 + 0)) & 1u);
            float d1 = cv1[t].y - (float)((b >> (k0 + 1)) & 1u);
            float d2 = cv1[t].z - (float)((b >> (k0 + 2)) & 1u);
            float d3 = cv1[t].w - (float)((b >> (k0 + 3)) & 1u);
            clsL += d0 * d0 + d1 * d1 + d2 * d2 + d3 * d3;
        }
    }

    // ================= reductions ============================================
    for (int off = 32; off > 0; off >>= 1) {
        coordL += __shfl_down(coordL, off);
        objL   += __shfl_down(objL, off);
        noobjL += __shfl_down(noobjL, off);
        clsL   += __shfl_down(clsL, off);
    }
    if (lane == 0) {
        s_red[wave][0] = coordL;
        s_red[wave][1] = objL;
        s_red[wave][2] = noobjL;
        s_red[wave][3] = clsL;
    }
    __syncthreads();

    if (threadIdx.x == 0) {
        float c0 = 0.f, c1 = 0.f, c2 = 0.f, c3 = 0.f;
        for (int w = 0; w < BPB; ++w) {
            c0 += s_red[w][0];
            c1 += s_red[w][1];
            c2 += s_red[w][2];
            c3 += s_red[w][3];
        }
        ws[0 * NBLK + blockIdx.x] = c0 * 5.0f;   // COORD_W
        ws[1 * NBLK + blockIdx.x] = c1;
        ws[2 * NBLK + blockIdx.x] = c2 * 0.5f;   // NOOBJ_W
        ws[3 * NBLK + blockIdx.x] = c3;
    }
}

// One wave per loss component; coalesced reads of its NBLK partials.
__global__ __launch_bounds__(256) void reduce_kernel(
    const float* __restrict__ ws, float* __restrict__ out)
{
    const int wave = threadIdx.x >> 6;   // 0..3 = component
    const int lane = threadIdx.x & 63;
    const float* src = ws + wave * NBLK;
    float s = 0.0f;
    for (int i = lane; i < NBLK; i += 64) s += src[i];
    for (int off = 32; off > 0; off >>= 1) s += __shfl_down(s, off);
    if (lane == 0) out[wave] = s;
}

extern "C" void kernel_launch(void* const* d_in, const int* in_sizes, int n_in,
                              void* d_out, int out_size, void* d_ws, size_t ws_size,
                              hipStream_t stream) {
    const float* preConf  = (const float*)d_in[0];
    const float* preBoxes = (const float*)d_in[1];
    const float* preCls   = (const float*)d_in[2];
    const float* gtBox    = (const float*)d_in[3];
    const int*   gtLab    = (const int*)d_in[4];
    float* out = (float*)d_out;
    float* ws  = (float*)d_ws;

    yolo_loss_kernel<<<NBLK, THREADS, 0, stream>>>(
        preConf, preBoxes, preCls, gtBox, gtLab, ws);
    reduce_kernel<<<1, 256, 0, stream>>>(ws, out);
}